// Round 1
// baseline (2904.934 us; speedup 1.0000x reference)
//
#include <hip/hip_runtime.h>
#include <math.h>

#define NN 100000     // nodes
#define NE 1600000    // edges
#define D  128        // feature dim
#define NL 3          // layers

// ---------------- degree / normalization ----------------

__global__ __launch_bounds__(256) void k_count(const int* __restrict__ dstv,
                                               unsigned* __restrict__ deg) {
  int i = blockIdx.x * 256 + threadIdx.x;
  if (i < NE) atomicAdd(&deg[dstv[i]], 1u);
}

__global__ __launch_bounds__(256) void k_dinv(const unsigned* __restrict__ deg,
                                              float* __restrict__ dinv) {
  int i = blockIdx.x * 256 + threadIdx.x;
  if (i < NN) dinv[i] = 1.0f / sqrtf((float)(deg[i] + 1u));
}

// ---------------- CSR build: 3-stage exclusive scan ----------------

__global__ __launch_bounds__(256) void k_scan1(const unsigned* __restrict__ deg,
                                               unsigned* __restrict__ bsum) {
  __shared__ unsigned s[256];
  int t = threadIdx.x;
  int i = blockIdx.x * 256 + t;
  s[t] = (i < NN) ? deg[i] : 0u;
  __syncthreads();
  for (int off = 128; off > 0; off >>= 1) {
    if (t < off) s[t] += s[t + off];
    __syncthreads();
  }
  if (t == 0) bsum[blockIdx.x] = s[0];
}

__global__ __launch_bounds__(512) void k_scan2(const unsigned* __restrict__ bsum,
                                               unsigned* __restrict__ boff, int nb) {
  __shared__ unsigned s[512];
  int t = threadIdx.x;
  unsigned v = (t < nb) ? bsum[t] : 0u;
  s[t] = v;
  __syncthreads();
  for (int off = 1; off < 512; off <<= 1) {
    unsigned x = (t >= off) ? s[t - off] : 0u;
    __syncthreads();
    s[t] += x;
    __syncthreads();
  }
  if (t < nb) boff[t] = s[t] - v;   // exclusive
}

__global__ __launch_bounds__(256) void k_scan3(const unsigned* __restrict__ deg,
                                               const unsigned* __restrict__ boff,
                                               unsigned* __restrict__ rowptr) {
  __shared__ unsigned s[256];
  int t = threadIdx.x;
  int i = blockIdx.x * 256 + t;
  unsigned v = (i < NN) ? deg[i] : 0u;
  s[t] = v;
  __syncthreads();
  for (int off = 1; off < 256; off <<= 1) {
    unsigned x = (t >= off) ? s[t - off] : 0u;
    __syncthreads();
    s[t] += x;
    __syncthreads();
  }
  unsigned excl = s[t] - v + boff[blockIdx.x];
  if (i <= NN) rowptr[i] = excl;    // i==NN lands exactly on total == NE
}

__global__ __launch_bounds__(256) void k_fill(const int* __restrict__ srcv,
                                              const int* __restrict__ dstv,
                                              const float* __restrict__ dinv,
                                              const unsigned* __restrict__ rowptr,
                                              unsigned* __restrict__ fillcnt,
                                              int* __restrict__ colv,
                                              float* __restrict__ enorm) {
  int i = blockIdx.x * 256 + threadIdx.x;
  if (i >= NE) return;
  int d = dstv[i];
  int s = srcv[i];
  unsigned pos = rowptr[d] + atomicAdd(&fillcnt[d], 1u);
  colv[pos] = s;
  enorm[pos] = dinv[s] * dinv[d];
}

// ---------------- GEMM: hw = h @ W  (f32 vector ALU, W in LDS) ----------------
// Block: 256 threads (4 waves), 64 rows per block. Each wave: 16 rows in 4
// groups of 4; each lane computes 4 rows x 2 cols (cols 2*lane, 2*lane+1).

__global__ __launch_bounds__(256) void k_gemm(const float* __restrict__ A,
                                              const float* __restrict__ W,
                                              float* __restrict__ Bout) {
  __shared__ float Wl[D * D];   // 64 KB
  const int t = threadIdx.x;
#pragma unroll
  for (int i = 0; i < 16; ++i) {
    int off = (t + i * 256) * 4;
    *(float4*)&Wl[off] = *(const float4*)&W[off];
  }
  __syncthreads();

  const int wave = t >> 6, lane = t & 63;
  const int row0 = blockIdx.x * 64 + wave * 16;

  for (int g = 0; g < 4; ++g) {
    const int r0 = row0 + g * 4;
    float acc[4][2];
#pragma unroll
    for (int r = 0; r < 4; ++r) { acc[r][0] = 0.f; acc[r][1] = 0.f; }

    const float* Ar[4];
#pragma unroll
    for (int r = 0; r < 4; ++r) {
      int rr = r0 + r;
      if (rr > NN - 1) rr = NN - 1;           // clamp reads; writes guarded
      Ar[r] = A + (size_t)rr * D;
    }

    for (int kc = 0; kc < D; kc += 16) {
      float hv[4][16];
#pragma unroll
      for (int r = 0; r < 4; ++r) {
#pragma unroll
        for (int q = 0; q < 4; ++q)
          *(float4*)&hv[r][q * 4] = *(const float4*)&Ar[r][kc + q * 4];
      }
#pragma unroll
      for (int kk = 0; kk < 16; ++kk) {
        const float2 wv = *(const float2*)&Wl[(kc + kk) * D + lane * 2];
#pragma unroll
        for (int r = 0; r < 4; ++r) {
          acc[r][0] = fmaf(hv[r][kk], wv.x, acc[r][0]);
          acc[r][1] = fmaf(hv[r][kk], wv.y, acc[r][1]);
        }
      }
    }

#pragma unroll
    for (int r = 0; r < 4; ++r) {
      int rr = r0 + r;
      if (rr < NN) {
        float2 o; o.x = acc[r][0]; o.y = acc[r][1];
        *(float2*)&Bout[(size_t)rr * D + lane * 2] = o;
      }
    }
  }
}

// ---------------- Aggregation: one wave per node, fused bias+ReLU ----------------

__global__ __launch_bounds__(256) void k_agg(const float* __restrict__ hw,
                                             const int* __restrict__ colv,
                                             const float* __restrict__ enorm,
                                             const unsigned* __restrict__ rowptr,
                                             const float* __restrict__ dinv,
                                             const float* __restrict__ bias,
                                             float* __restrict__ hout) {
  const int wid = (blockIdx.x * 256 + threadIdx.x) >> 6;   // node id
  const int lane = threadIdx.x & 63;
  if (wid >= NN) return;

  const float di = dinv[wid];
  const float sn = di * di;
  float2 v = *(const float2*)&hw[(size_t)wid * D + lane * 2];
  float ax = v.x * sn, ay = v.y * sn;

  const unsigned s = rowptr[wid], e = rowptr[wid + 1];
  for (unsigned j = s; j < e; ++j) {
    const int src = colv[j];          // wave-uniform load
    const float w = enorm[j];         // wave-uniform load
    const float2 u = *(const float2*)&hw[(size_t)src * D + lane * 2];
    ax = fmaf(w, u.x, ax);
    ay = fmaf(w, u.y, ay);
  }

  const float2 b = *(const float2*)&bias[lane * 2];
  ax += b.x; ay += b.y;
  ax = ax > 0.f ? ax : 0.f;
  ay = ay > 0.f ? ay : 0.f;
  float2 o; o.x = ax; o.y = ay;
  *(float2*)&hout[(size_t)wid * D + lane * 2] = o;
}

// ---------------- Head GEMV: out = h @ head_W + head_b ----------------

__global__ __launch_bounds__(256) void k_head(const float* __restrict__ h,
                                              const float* __restrict__ hW,
                                              const float* __restrict__ hb,
                                              float* __restrict__ out) {
  const int wid = (blockIdx.x * 256 + threadIdx.x) >> 6;
  const int lane = threadIdx.x & 63;
  if (wid >= NN) return;
  const float* hr = h + (size_t)wid * D;
  float sum = hr[lane] * hW[lane] + hr[lane + 64] * hW[lane + 64];
#pragma unroll
  for (int off = 32; off > 0; off >>= 1) sum += __shfl_down(sum, off, 64);
  if (lane == 0) out[wid] = sum + hb[0];
}

// ---------------- launch ----------------

extern "C" void kernel_launch(void* const* d_in, const int* in_sizes, int n_in,
                              void* d_out, int out_size, void* d_ws, size_t ws_size,
                              hipStream_t stream) {
  const float* x   = (const float*)d_in[0];
  const int*   ei  = (const int*)d_in[1];
  const float* Ws  = (const float*)d_in[2];
  const float* bs  = (const float*)d_in[3];
  const float* hW  = (const float*)d_in[4];
  const float* hb  = (const float*)d_in[5];
  float* out = (float*)d_out;

  char* w = (char*)d_ws;
  float*    bufA    = (float*)w;    w += (size_t)NN * D * 4;       // 51.2 MB
  float*    bufB    = (float*)w;    w += (size_t)NN * D * 4;       // 51.2 MB
  int*      colv    = (int*)w;      w += (size_t)NE * 4;           // 6.4 MB
  float*    enorm   = (float*)w;    w += (size_t)NE * 4;           // 6.4 MB
  unsigned* rowptr  = (unsigned*)w; w += (size_t)(NN + 16) * 4;
  unsigned* deg     = (unsigned*)w; w += (size_t)NN * 4;
  unsigned* fillcnt = (unsigned*)w; w += (size_t)NN * 4;
  float*    dinv    = (float*)w;    w += (size_t)NN * 4;
  unsigned* bsum    = (unsigned*)w; w += 512 * 4;
  unsigned* boff    = (unsigned*)w; w += 512 * 4;

  const int* srcv = ei;
  const int* dstv = ei + NE;

  hipMemsetAsync(deg,     0, (size_t)NN * 4, stream);
  hipMemsetAsync(fillcnt, 0, (size_t)NN * 4, stream);

  const int NB = (NN + 255) / 256;   // 391

  k_count<<<(NE + 255) / 256, 256, 0, stream>>>(dstv, deg);
  k_dinv <<<NB, 256, 0, stream>>>(deg, dinv);
  k_scan1<<<NB, 256, 0, stream>>>(deg, bsum);
  k_scan2<<<1, 512, 0, stream>>>(bsum, boff, NB);
  k_scan3<<<NB, 256, 0, stream>>>(deg, boff, rowptr);
  k_fill <<<(NE + 255) / 256, 256, 0, stream>>>(srcv, dstv, dinv, rowptr, fillcnt, colv, enorm);

  const float* hin = x;
  for (int l = 0; l < NL; ++l) {
    k_gemm<<<(NN + 63) / 64, 256, 0, stream>>>(hin, Ws + (size_t)l * D * D, bufA);
    k_agg <<<(NN + 3) / 4, 256, 0, stream>>>(bufA, colv, enorm, rowptr, dinv,
                                             bs + (size_t)l * D, bufB);
    hin = bufB;
  }

  k_head<<<(NN + 3) / 4, 256, 0, stream>>>(bufB, hW, hb, out);
}